// Round 1
// baseline (1361.445 us; speedup 1.0000x reference)
//
#include <hip/hip_runtime.h>
#include <hip/hip_bf16.h>
#include <cstddef>

#define BATCH 16
#define CC 128
#define NN 16384
#define GROUPS 32
#define EPSV 1e-5f

// workspace float offsets
#define OFF_MU    0                 // 512
#define OFF_RSTD  512               // 512
#define OFF_WEFF  1024              // [b][c][o] : 16*128*256 = 524288
#define OFF_BEFF  525312            // 16*256 = 4096
#define OFF_CTX   529408            // 16*128*32 = 65536
#define OFF_A     594944            // 16*128*128 = 262144
#define OFF_CB    857088            // 16*128 = 2048
#define BASE_FLOATS 859136
#define PART_STRIDE 4224            // 4096 ctx partial + 128 Z partial

// ---------------- K1: GroupNorm stats ----------------
__global__ void k1_gnstats(const float* __restrict__ x, float* __restrict__ wsf) {
    int bg = blockIdx.x;            // b*32+g ; group data is contiguous 65536 floats
    int tid = threadIdx.x;
    const float4* p = (const float4*)(x + (size_t)bg * 65536);
    float s = 0.f, sq = 0.f;
    #pragma unroll 4
    for (int i = 0; i < 64; ++i) {
        float4 v = p[i * 256 + tid];
        s  += v.x + v.y + v.z + v.w;
        sq += v.x*v.x + v.y*v.y + v.z*v.z + v.w*v.w;
    }
    __shared__ float rs[256], rq[256];
    rs[tid] = s; rq[tid] = sq; __syncthreads();
    for (int off = 128; off > 0; off >>= 1) {
        if (tid < off) { rs[tid] += rs[tid+off]; rq[tid] += rq[tid+off]; }
        __syncthreads();
    }
    if (tid == 0) {
        float mean = rs[0] * (1.f/65536.f);
        float var  = rq[0] * (1.f/65536.f) - mean*mean;
        wsf[OFF_MU + bg]   = mean;
        wsf[OFF_RSTD + bg] = rsqrtf(var + EPSV);
    }
}

// ---------------- K2: effective kv weights (GN folded in) ----------------
__global__ void k2_weff(const float* __restrict__ kv_w, const float* __restrict__ kv_b,
                        const float* __restrict__ gn_scale, const float* __restrict__ gn_bias,
                        float* __restrict__ wsf) {
    int b = blockIdx.x, o = threadIdx.x;   // 16 x 256
    const float* mu = wsf + OFF_MU + b * GROUPS;
    const float* rs = wsf + OFF_RSTD + b * GROUPS;
    float bacc = 0.f;
    float* wbase = wsf + OFF_WEFF + (size_t)b * 128 * 256;
    for (int c = 0; c < 128; ++c) {
        int g = c >> 2;
        float r = rs[g], m = mu[g];
        float sc = gn_scale[c] * r;
        float w = kv_w[o * 128 + c];
        wbase[c * 256 + o] = w * sc;                    // [c][o] layout: coalesced store+load
        bacc += w * (gn_bias[c] - m * sc);
    }
    wsf[OFF_BEFF + b * 256 + o] = kv_b[o] + bacc;
}

// ---------------- K3: fused kv-proj + streaming softmax-attention accum ----------------
#define XP 132
__global__ __launch_bounds__(256) void k3_attn(const float* __restrict__ x,
                                               const float* __restrict__ wsf,
                                               float* __restrict__ part) {
    int b = blockIdx.y;
    int chunk = blockIdx.x;
    int nbpb = gridDim.x;
    int ppb = NN / nbpb;
    int n0 = chunk * ppb;
    int tid = threadIdx.x;

    __shared__ __align__(16) float xs[32 * XP];
    __shared__ __align__(16) float kvs[32 * 256];

    // per-thread kv output row o = tid, weights in registers (coalesced [c][o] loads)
    float w[128];
    {
        const float* wbase = wsf + OFF_WEFF + (size_t)b * 128 * 256;
        #pragma unroll
        for (int c = 0; c < 128; ++c) w[c] = wbase[c * 256 + tid];
    }
    float beff = wsf[OFF_BEFF + b * 256 + tid];

    int hd = tid >> 1;                                  // context row this thread accumulates
    int vbase = 128 + (hd >> 5) * 32 + (tid & 1) * 16;  // v channels for its 16 e's
    float ctx[16];
    #pragma unroll
    for (int i = 0; i < 16; ++i) ctx[i] = 0.f;
    float zacc = 0.f;

    int c_l  = tid >> 1;       // staging: channel
    int half = tid & 1;        // staging: 16-pixel half

    for (int t = 0; t < ppb / 32; ++t) {
        int np0 = n0 + t * 32;
        // stage 32 pixels x 128 channels of x into LDS (pixel-major, padded)
        {
            const float* src = x + ((size_t)b * CC + c_l) * NN + np0 + half * 16;
            #pragma unroll
            for (int k = 0; k < 4; ++k) {
                float4 v = ((const float4*)src)[k];
                int p = half * 16 + k * 4;
                xs[(p+0)*XP + c_l] = v.x;
                xs[(p+1)*XP + c_l] = v.y;
                xs[(p+2)*XP + c_l] = v.z;
                xs[(p+3)*XP + c_l] = v.w;
            }
        }
        __syncthreads();
        // phase 1: kv[o] = W_b[o,:] . x[:,p] + beff ; k-rows get exp()
        for (int p = 0; p < 32; ++p) {
            float a0=0.f, a1=0.f, a2=0.f, a3=0.f;
            const float* xp = &xs[p * XP];
            #pragma unroll
            for (int c = 0; c < 128; c += 4) {
                float4 v = *(const float4*)(xp + c);
                a0 += w[c+0]*v.x; a1 += w[c+1]*v.y; a2 += w[c+2]*v.z; a3 += w[c+3]*v.w;
            }
            float kv = (a0 + a1) + (a2 + a3) + beff;
            kvs[p * 256 + tid] = (tid < 128) ? __expf(kv) : kv;
        }
        __syncthreads();
        // phase 2: ctx[hd][e] += ek[hd] * v[e] ; Z[hd] += ek
        for (int p = 0; p < 32; ++p) {
            float ek = kvs[p * 256 + hd];
            const float4* vv = (const float4*)&kvs[p * 256 + vbase];
            #pragma unroll
            for (int j = 0; j < 4; ++j) {
                float4 v = vv[j];
                ctx[j*4+0] += ek * v.x; ctx[j*4+1] += ek * v.y;
                ctx[j*4+2] += ek * v.z; ctx[j*4+3] += ek * v.w;
            }
            if ((tid & 1) == 0) zacc += ek;
        }
        __syncthreads();
    }
    // write per-block partials
    float* pb = part + (size_t)(b * nbpb + chunk) * PART_STRIDE;
    int e0 = (tid & 1) * 16;
    float4* dst = (float4*)&pb[hd * 32 + e0];
    dst[0] = make_float4(ctx[0], ctx[1], ctx[2], ctx[3]);
    dst[1] = make_float4(ctx[4], ctx[5], ctx[6], ctx[7]);
    dst[2] = make_float4(ctx[8], ctx[9], ctx[10], ctx[11]);
    dst[3] = make_float4(ctx[12], ctx[13], ctx[14], ctx[15]);
    if ((tid & 1) == 0) pb[4096 + hd] = zacc;
}

// ---------------- K4: reduce partials -> context = S/Z ----------------
__global__ void k4_reduce(const float* __restrict__ part, float* __restrict__ wsf, int nbpb) {
    int b = blockIdx.x; int tid = threadIdx.x;
    int hd = tid >> 1, e0 = (tid & 1) * 16;
    float s[16];
    #pragma unroll
    for (int j = 0; j < 16; ++j) s[j] = 0.f;
    float z = 0.f;
    for (int i = 0; i < nbpb; ++i) {
        const float* pb = part + (size_t)(b * nbpb + i) * PART_STRIDE;
        #pragma unroll
        for (int j4 = 0; j4 < 4; ++j4) {
            float4 v = *(const float4*)&pb[hd * 32 + e0 + j4 * 4];
            s[j4*4+0] += v.x; s[j4*4+1] += v.y; s[j4*4+2] += v.z; s[j4*4+3] += v.w;
        }
        if (tid < 128) z += pb[4096 + tid];
    }
    __shared__ float zs[128];
    if (tid < 128) zs[tid] = z;
    __syncthreads();
    float zi = 1.f / zs[hd];
    float* cg = wsf + OFF_CTX + (size_t)b * 4096;
    #pragma unroll
    for (int j = 0; j < 16; ++j) cg[hd * 32 + e0 + j] = s[j] * zi;
}

// ---------------- K5: A_b = out_w . blockdiag(ctx^T) . q_w ; c_b ----------------
__global__ void k5_buildA(const float* __restrict__ out_w, const float* __restrict__ q_w,
                          const float* __restrict__ q_b, const float* __restrict__ out_b,
                          float* __restrict__ wsf) {
    int b = blockIdx.x; int tid = threadIdx.x;
    __shared__ __align__(16) float ctx_s[4096];
    __shared__ __align__(16) float T_s[64 * 132];
    {
        const float4* src = (const float4*)(wsf + OFF_CTX + (size_t)b * 4096);
        float4* dst = (float4*)ctx_s;
        for (int i = tid; i < 1024; i += 256) dst[i] = src[i];
    }
    __syncthreads();
    for (int oh = 0; oh < 128; oh += 64) {
        int o = oh + (tid >> 2);
        int q4 = tid & 3;
        // phase A: T[o][j=h*32+d] = sum_e out_w[o][h*32+e] * ctx[h][d][e]
        {
            int jq = q4 * 32;
            int h = jq >> 5;
            float ow[32];
            #pragma unroll
            for (int e4 = 0; e4 < 8; ++e4) {
                float4 v = *(const float4*)&out_w[o * 128 + h * 32 + e4 * 4];
                ow[e4*4+0]=v.x; ow[e4*4+1]=v.y; ow[e4*4+2]=v.z; ow[e4*4+3]=v.w;
            }
            for (int d = 0; d < 32; ++d) {
                float acc = 0.f;
                const float* cp = &ctx_s[(h * 32 + d) * 32];
                #pragma unroll
                for (int e = 0; e < 32; ++e) acc += ow[e] * cp[e];
                T_s[(o - oh) * 132 + jq + d] = acc;
            }
        }
        __syncthreads();
        // phase B: A[o][ci] = sum_j T[o][j] * q_w[j][ci] ; cb[o]
        {
            int cq = q4 * 32;
            float a[32];
            #pragma unroll
            for (int i = 0; i < 32; ++i) a[i] = 0.f;
            for (int j = 0; j < 128; ++j) {
                float tv = T_s[(o - oh) * 132 + j];
                const float4* qv = (const float4*)&q_w[j * 128 + cq];
                #pragma unroll
                for (int i4 = 0; i4 < 8; ++i4) {
                    float4 v = qv[i4];
                    a[i4*4+0] += tv*v.x; a[i4*4+1] += tv*v.y;
                    a[i4*4+2] += tv*v.z; a[i4*4+3] += tv*v.w;
                }
            }
            float* Ao = wsf + OFF_A + ((size_t)b * 128 + o) * 128 + cq;
            #pragma unroll
            for (int i = 0; i < 32; ++i) Ao[i] = a[i];
            if (q4 == 0) {
                float cb = 0.f;
                for (int j = 0; j < 128; ++j) cb += T_s[(o - oh) * 132 + j] * q_b[j];
                wsf[OFF_CB + b * 128 + o] = cb + out_b[o];
            }
        }
        __syncthreads();
    }
}

// ---------------- K6: y = A_b . cond + c_b ----------------
__global__ __launch_bounds__(256) void k6_final(const float* __restrict__ cond,
                                                const float* __restrict__ wsf,
                                                float* __restrict__ y) {
    int b = blockIdx.y;
    int tid = threadIdx.x;
    int n = blockIdx.x * 256 + tid;
    __shared__ __align__(16) float A_s[8192];

    float cnd[128];
    #pragma unroll
    for (int c = 0; c < 128; ++c) cnd[c] = cond[((size_t)b * CC + c) * NN + n];
    const float* cb = wsf + OFF_CB + b * 128;

    for (int half = 0; half < 2; ++half) {
        __syncthreads();   // protect previous-half readers
        {
            const float4* src = (const float4*)(wsf + OFF_A + (size_t)b * 16384 + half * 8192);
            float4* dst = (float4*)A_s;
            #pragma unroll
            for (int i = 0; i < 8; ++i) dst[i * 256 + tid] = src[i * 256 + tid];
        }
        __syncthreads();
        for (int o2 = 0; o2 < 64; o2 += 2) {
            int o = half * 64 + o2;
            float acc0 = cb[o], acc1 = cb[o + 1];
            #pragma unroll
            for (int c4 = 0; c4 < 32; ++c4) {
                float4 v0 = *(const float4*)&A_s[(o2    ) * 128 + c4 * 4];
                float4 v1 = *(const float4*)&A_s[(o2 + 1) * 128 + c4 * 4];
                acc0 += v0.x*cnd[c4*4] + v0.y*cnd[c4*4+1] + v0.z*cnd[c4*4+2] + v0.w*cnd[c4*4+3];
                acc1 += v1.x*cnd[c4*4] + v1.y*cnd[c4*4+1] + v1.z*cnd[c4*4+2] + v1.w*cnd[c4*4+3];
            }
            y[((size_t)b * CC + o    ) * NN + n] = acc0;
            y[((size_t)b * CC + o + 1) * NN + n] = acc1;
        }
    }
}

extern "C" void kernel_launch(void* const* d_in, const int* in_sizes, int n_in,
                              void* d_out, int out_size, void* d_ws, size_t ws_size,
                              hipStream_t stream) {
    const float* x        = (const float*)d_in[0];
    const float* cond     = (const float*)d_in[1];
    const float* gn_scale = (const float*)d_in[2];
    const float* gn_bias  = (const float*)d_in[3];
    const float* kv_w     = (const float*)d_in[4];
    const float* kv_b     = (const float*)d_in[5];
    const float* q_w      = (const float*)d_in[6];
    const float* q_b      = (const float*)d_in[7];
    const float* out_w    = (const float*)d_in[8];
    const float* out_b    = (const float*)d_in[9];
    float* y   = (float*)d_out;
    float* wsf = (float*)d_ws;

    const int nbpb = 32;  // chunks per batch for K3
    size_t need = (size_t)(BASE_FLOATS + BATCH * nbpb * PART_STRIDE) * sizeof(float);
    float* part = wsf + BASE_FLOATS;
    if (ws_size < need) part = y;   // safe: partials fully consumed by K4 before K6 writes y

    k1_gnstats<<<512, 256, 0, stream>>>(x, wsf);
    k2_weff<<<16, 256, 0, stream>>>(kv_w, kv_b, gn_scale, gn_bias, wsf);
    k3_attn<<<dim3(nbpb, BATCH), 256, 0, stream>>>(x, wsf, part);
    k4_reduce<<<BATCH, 256, 0, stream>>>(part, wsf, nbpb);
    k5_buildA<<<BATCH, 256, 0, stream>>>(out_w, q_w, q_b, out_b, wsf);
    k6_final<<<dim3(64, BATCH), 256, 0, stream>>>(cond, wsf, y);
}

// Round 2
// 575.336 us; speedup vs baseline: 2.3663x; 2.3663x over previous
//
#include <hip/hip_runtime.h>
#include <hip/hip_bf16.h>
#include <cstddef>

#define BATCH 16
#define CC 128
#define NN 16384
#define GROUPS 32
#define EPSV 1e-5f

// workspace float offsets
#define OFF_MU    0          // 512
#define OFF_RSTD  512        // 512
#define OFF_BEFF  1024       // 4096
#define OFF_CTX   5120       // 65536
#define OFF_CB    70656      // 2048
#define OFF_AOLD  72704      // 262144 (fp32 A for fallback k6)
#define OFF_WH    334848     // 262144 fl = 524288 ushorts (W_eff hi frags)
#define OFF_AH    596992     // 131072 fl (A_b hi frags)
#define OFF_AL    728064     // 131072 fl (A_b lo frags)
#define OFF_PART  859136     // 512*4224 = 2162688 fl
#define OFF_XT    3021824    // xt_h (16777216 fl) then xt_l
#define PART_STRIDE 4224

typedef __attribute__((ext_vector_type(8))) short bf8;
typedef __attribute__((ext_vector_type(4))) float f4;
#define MFMA16(a,b,c) __builtin_amdgcn_mfma_f32_16x16x32_bf16(a,b,c,0,0,0)

__device__ inline unsigned short bf16_rtn(float f) {
    unsigned u = __builtin_bit_cast(unsigned, f);
    unsigned r = (u + 0x7FFFu + ((u >> 16) & 1u)) >> 16;
    return (unsigned short)r;
}
__device__ inline float bf16_f(unsigned short h) {
    unsigned u = ((unsigned)h) << 16;
    return __builtin_bit_cast(float, u);
}

// ---------------- K1: GroupNorm stats (unchanged) ----------------
__global__ void k1_gnstats(const float* __restrict__ x, float* __restrict__ wsf) {
    int bg = blockIdx.x;
    int tid = threadIdx.x;
    const float4* p = (const float4*)(x + (size_t)bg * 65536);
    float s = 0.f, sq = 0.f;
    #pragma unroll 4
    for (int i = 0; i < 64; ++i) {
        float4 v = p[i * 256 + tid];
        s  += v.x + v.y + v.z + v.w;
        sq += v.x*v.x + v.y*v.y + v.z*v.z + v.w*v.w;
    }
    __shared__ float rs[256], rq[256];
    rs[tid] = s; rq[tid] = sq; __syncthreads();
    for (int off = 128; off > 0; off >>= 1) {
        if (tid < off) { rs[tid] += rs[tid+off]; rq[tid] += rq[tid+off]; }
        __syncthreads();
    }
    if (tid == 0) {
        float mean = rs[0] * (1.f/65536.f);
        float var  = rq[0] * (1.f/65536.f) - mean*mean;
        wsf[OFF_MU + bg]   = mean;
        wsf[OFF_RSTD + bg] = rsqrtf(var + EPSV);
    }
}

// ---------------- K1a: transpose + bf16 hi/lo split:  [c][n] f32 -> [p][c] bf16 x2 ----------------
#define K1A_W 136
__global__ __launch_bounds__(256) void k1a_transpose(const float* __restrict__ src,
        unsigned short* __restrict__ dh, unsigned short* __restrict__ dl) {
    int b = blockIdx.y; int p0 = blockIdx.x * 128; int t = threadIdx.x;
    __shared__ unsigned short lh[128 * K1A_W], ll[128 * K1A_W];
    int p = t & 127, chalf = t >> 7;
    const float* sp = src + (size_t)b * CC * NN + p0 + p;
    #pragma unroll 8
    for (int i = 0; i < 64; ++i) {
        int c = i * 2 + chalf;
        float v = sp[(size_t)c * NN];
        unsigned short h = bf16_rtn(v);
        unsigned short l = bf16_rtn(v - bf16_f(h));
        lh[p * K1A_W + c] = h;
        ll[p * K1A_W + c] = l;
    }
    __syncthreads();
    int pr = t >> 4, c8 = (t & 15) * 8;
    #pragma unroll
    for (int j = 0; j < 8; ++j) {
        int p2 = j * 16 + pr;
        bf8 vh = *(const bf8*)&lh[p2 * K1A_W + c8];
        bf8 vl = *(const bf8*)&ll[p2 * K1A_W + c8];
        size_t off = ((size_t)b * NN + p0 + p2) * 128 + c8;
        *(bf8*)&dh[off] = vh;
        *(bf8*)&dl[off] = vl;
    }
}

// ---------------- K2: effective kv weights, bf16-hi frag-packed ----------------
__global__ void k2_weff(const float* __restrict__ kv_w, const float* __restrict__ kv_b,
                        const float* __restrict__ gn_scale, const float* __restrict__ gn_bias,
                        float* __restrict__ wsf, unsigned short* __restrict__ wh) {
    int b = blockIdx.x, o = threadIdx.x;   // 16 x 256
    const float* mu = wsf + OFF_MU + b * GROUPS;
    const float* rs = wsf + OFF_RSTD + b * GROUPS;
    float w[128]; float bacc = 0.f;
    #pragma unroll
    for (int c = 0; c < 128; ++c) {
        int g = c >> 2;
        float sc = gn_scale[c] * rs[g];
        float kw = kv_w[o * 128 + c];
        w[c] = kw * sc;
        bacc += kw * (gn_bias[c] - mu[g] * sc);
    }
    wsf[OFF_BEFF + b * 256 + o] = kv_b[o] + bacc;
    int h  = (o & 127) >> 5;
    int ct = ((o >> 4) & 1) + ((o >= 128) ? 2 : 0);
    int i  = o & 15;
    #pragma unroll
    for (int ks = 0; ks < 4; ++ks)
      #pragma unroll
      for (int eq = 0; eq < 4; ++eq) {
        bf8 pk;
        #pragma unroll
        for (int e = 0; e < 8; ++e) pk[e] = (short)bf16_rtn(w[ks*32 + eq*8 + e]);
        int lane = i + 16 * eq;
        size_t fo = ((((size_t)b * 4 + h) * 4 + ct) * 4 + ks) * 512 + (size_t)lane * 8;
        *(bf8*)&wh[fo] = pk;
      }
}

// ---------------- K3: MFMA kv-proj + streaming softmax-attention ----------------
__global__ __launch_bounds__(256, 2) void k3_attn(
    const unsigned short* __restrict__ xh, const unsigned short* __restrict__ xl,
    const unsigned short* __restrict__ wh, const float* __restrict__ wsf,
    float* __restrict__ part)
{
    int b = blockIdx.y, chunk = blockIdx.x;        // 32 chunks x 512 px
    int t = threadIdx.x, h = t >> 6, l = t & 63;
    int l15 = l & 15, lq = l >> 4;

    __shared__ unsigned short lds[4][2][32 * 64];  // [wave][ek|v][32 rows][64 px]

    bf8 W[4][4];                                    // [ct][ks], hi only
    #pragma unroll
    for (int ct = 0; ct < 4; ++ct)
      #pragma unroll
      for (int ks = 0; ks < 4; ++ks)
        W[ct][ks] = ((const bf8*)wh)[((((size_t)b*4 + h)*4 + ct)*4 + ks)*64 + l];

    float bk[4];
    #pragma unroll
    for (int ct = 0; ct < 4; ++ct) {
        int o = (ct < 2) ? (32*h + 16*ct + l15) : (128 + 32*h + 16*(ct-2) + l15);
        bk[ct] = wsf[OFF_BEFF + b * 256 + o];
    }

    bf8 ones;
    #pragma unroll
    for (int j = 0; j < 8; ++j) ones[j] = (short)0x3F80;

    f4 ctx[2][2]; f4 zac[2];
    #pragma unroll
    for (int i = 0; i < 2; ++i) {
        zac[i] = (f4){0,0,0,0};
        #pragma unroll
        for (int j = 0; j < 2; ++j) ctx[i][j] = (f4){0,0,0,0};
    }

    int pbase = chunk * 512;
    for (int tile = 0; tile < 8; ++tile) {
        int tp = pbase + tile * 64;
        f4 acc[4][4];                               // [pt][ct]
        #pragma unroll
        for (int pt = 0; pt < 4; ++pt)
          #pragma unroll
          for (int ct = 0; ct < 4; ++ct) acc[pt][ct] = (f4){0,0,0,0};

        #pragma unroll
        for (int pt = 0; pt < 4; ++pt) {
            size_t rowoff = ((size_t)b * NN + tp + pt*16 + l15) * 128 + lq * 8;
            #pragma unroll
            for (int ks = 0; ks < 4; ++ks) {
                bf8 ah = *(const bf8*)(xh + rowoff + ks*32);
                bf8 al = *(const bf8*)(xl + rowoff + ks*32);
                #pragma unroll
                for (int ct = 0; ct < 4; ++ct) {
                    acc[pt][ct] = MFMA16(ah, W[ct][ks], acc[pt][ct]);
                    acc[pt][ct] = MFMA16(al, W[ct][ks], acc[pt][ct]);
                }
            }
        }
        // bias + exp(k) -> LDS (bf16, XOR-swizzled rows)
        #pragma unroll
        for (int pt = 0; pt < 4; ++pt) {
            int p = pt * 16 + lq * 4;              // 4 consecutive px
            #pragma unroll
            for (int ct = 0; ct < 4; ++ct) {
                int row = (ct & 1) * 16 + l15;
                int sel = ct >> 1;                 // 0 = EK, 1 = V
                unsigned short pk[4];
                #pragma unroll
                for (int j = 0; j < 4; ++j) {
                    float v = acc[pt][ct][j] + bk[ct];
                    if (sel == 0) v = __expf(v);
                    pk[j] = bf16_rtn(v);
                }
                unsigned byte = ((unsigned)(row * 128 + p * 2)) ^ (((unsigned)(row & 7)) << 4);
                unsigned lo32 = (unsigned)pk[0] | ((unsigned)pk[1] << 16);
                unsigned hi32 = (unsigned)pk[2] | ((unsigned)pk[3] << 16);
                *(uint2*)((char*)&lds[h][sel][0] + byte) = make_uint2(lo32, hi32);
            }
        }
        // PV + Z (wave-local; compiler inserts lgkmcnt)
        #pragma unroll
        for (int ks2 = 0; ks2 < 2; ++ks2) {
            int p8 = ks2 * 32 + lq * 8;
            bf8 ek[2], vv[2];
            #pragma unroll
            for (int dt = 0; dt < 2; ++dt) {
                int row = dt * 16 + l15;
                unsigned byte = ((unsigned)(row * 128 + p8 * 2)) ^ (((unsigned)(row & 7)) << 4);
                ek[dt] = *(const bf8*)((char*)&lds[h][0][0] + byte);
                vv[dt] = *(const bf8*)((char*)&lds[h][1][0] + byte);
            }
            #pragma unroll
            for (int dt = 0; dt < 2; ++dt) {
                #pragma unroll
                for (int et = 0; et < 2; ++et)
                    ctx[dt][et] = MFMA16(ek[dt], vv[et], ctx[dt][et]);
                zac[dt] = MFMA16(ek[dt], ones, zac[dt]);
            }
        }
    }
    // partial write
    float* pb = part + (size_t)(b * 32 + chunk) * PART_STRIDE;
    #pragma unroll
    for (int dt = 0; dt < 2; ++dt) {
        #pragma unroll
        for (int et = 0; et < 2; ++et)
            #pragma unroll
            for (int j = 0; j < 4; ++j) {
                int d = 32*h + dt*16 + lq*4 + j;
                int e = et*16 + l15;
                pb[d * 32 + e] = ctx[dt][et][j];
            }
        if (l15 == 0)
            #pragma unroll
            for (int j = 0; j < 4; ++j)
                pb[4096 + 32*h + dt*16 + lq*4 + j] = zac[dt][j];
    }
}

// ---------------- K4: reduce partials -> context = S/Z (unchanged) ----------------
__global__ void k4_reduce(const float* __restrict__ part, float* __restrict__ wsf, int nbpb) {
    int b = blockIdx.x; int tid = threadIdx.x;
    int hd = tid >> 1, e0 = (tid & 1) * 16;
    float s[16];
    #pragma unroll
    for (int j = 0; j < 16; ++j) s[j] = 0.f;
    float z = 0.f;
    for (int i = 0; i < nbpb; ++i) {
        const float* pb = part + (size_t)(b * nbpb + i) * PART_STRIDE;
        #pragma unroll
        for (int j4 = 0; j4 < 4; ++j4) {
            float4 v = *(const float4*)&pb[hd * 32 + e0 + j4 * 4];
            s[j4*4+0] += v.x; s[j4*4+1] += v.y; s[j4*4+2] += v.z; s[j4*4+3] += v.w;
        }
        if (tid < 128) z += pb[4096 + tid];
    }
    __shared__ float zs[128];
    if (tid < 128) zs[tid] = z;
    __syncthreads();
    float zi = 1.f / zs[hd];
    float* cg = wsf + OFF_CTX + (size_t)b * 4096;
    #pragma unroll
    for (int j = 0; j < 16; ++j) cg[hd * 32 + e0 + j] = s[j] * zi;
}

// ---------------- K5: A_b = out_w . blockdiag(ctx^T) . q_w ; c_b ; frag-pack A ----------------
__global__ void k5_buildA(const float* __restrict__ out_w, const float* __restrict__ q_w,
                          const float* __restrict__ q_b, const float* __restrict__ out_b,
                          float* __restrict__ wsf,
                          unsigned short* __restrict__ ahp, unsigned short* __restrict__ alp) {
    int b = blockIdx.x; int tid = threadIdx.x;
    __shared__ __align__(16) float ctx_s[4096];
    __shared__ __align__(16) float T_s[64 * 132];
    {
        const float4* src = (const float4*)(wsf + OFF_CTX + (size_t)b * 4096);
        float4* dst = (float4*)ctx_s;
        for (int i = tid; i < 1024; i += 256) dst[i] = src[i];
    }
    __syncthreads();
    for (int oh = 0; oh < 128; oh += 64) {
        int o = oh + (tid >> 2);
        int q4 = tid & 3;
        {
            int jq = q4 * 32;
            int h = jq >> 5;
            float ow[32];
            #pragma unroll
            for (int e4 = 0; e4 < 8; ++e4) {
                float4 v = *(const float4*)&out_w[o * 128 + h * 32 + e4 * 4];
                ow[e4*4+0]=v.x; ow[e4*4+1]=v.y; ow[e4*4+2]=v.z; ow[e4*4+3]=v.w;
            }
            for (int d = 0; d < 32; ++d) {
                float acc = 0.f;
                const float* cp = &ctx_s[(h * 32 + d) * 32];
                #pragma unroll
                for (int e = 0; e < 32; ++e) acc += ow[e] * cp[e];
                T_s[(o - oh) * 132 + jq + d] = acc;
            }
        }
        __syncthreads();
        {
            int cq = q4 * 32;
            float a[32];
            #pragma unroll
            for (int i = 0; i < 32; ++i) a[i] = 0.f;
            for (int j = 0; j < 128; ++j) {
                float tv = T_s[(o - oh) * 132 + j];
                const float4* qv = (const float4*)&q_w[j * 128 + cq];
                #pragma unroll
                for (int i4 = 0; i4 < 8; ++i4) {
                    float4 v = qv[i4];
                    a[i4*4+0] += tv*v.x; a[i4*4+1] += tv*v.y;
                    a[i4*4+2] += tv*v.z; a[i4*4+3] += tv*v.w;
                }
            }
            float* Ao = wsf + OFF_AOLD + ((size_t)b * 128 + o) * 128 + cq;
            #pragma unroll
            for (int i = 0; i < 32; ++i) Ao[i] = a[i];
            // frag-pack hi/lo:  rt = o>>4, ks = q4, lane = (o&15) + 16*eq
            int rt = o >> 4;
            #pragma unroll
            for (int eq = 0; eq < 4; ++eq) {
                bf8 ph, pl;
                #pragma unroll
                for (int e = 0; e < 8; ++e) {
                    float v = a[eq*8 + e];
                    unsigned short hh = bf16_rtn(v);
                    ph[e] = (short)hh;
                    pl[e] = (short)bf16_rtn(v - bf16_f(hh));
                }
                int lane = (o & 15) + 16 * eq;
                size_t fo = ((((size_t)b * 8 + rt) * 4 + q4) * 64 + lane) * 8;
                *(bf8*)&ahp[fo] = ph;
                *(bf8*)&alp[fo] = pl;
            }
            if (q4 == 0) {
                float cb = 0.f;
                for (int j = 0; j < 128; ++j) cb += T_s[(o - oh) * 132 + j] * q_b[j];
                wsf[OFF_CB + b * 128 + o] = cb + out_b[o];
            }
        }
        __syncthreads();
    }
}

// ---------------- K6 (MFMA): y = A_b . cond + c_b ----------------
__global__ __launch_bounds__(256, 2) void k6_mfma(
    const unsigned short* __restrict__ ch, const unsigned short* __restrict__ cl,
    const unsigned short* __restrict__ ahp, const unsigned short* __restrict__ alp,
    const float* __restrict__ wsf, float* __restrict__ y)
{
    int b = blockIdx.y, chunk = blockIdx.x;
    int t = threadIdx.x, w = t >> 6, l = t & 63, l15 = l & 15, lq = l >> 4;
    bf8 Ah[2][4], Al[2][4];
    #pragma unroll
    for (int r = 0; r < 2; ++r)
      #pragma unroll
      for (int ks = 0; ks < 4; ++ks) {
        size_t idx = (((size_t)b * 8 + (2*w + r)) * 4 + ks) * 64 + l;
        Ah[r][ks] = ((const bf8*)ahp)[idx];
        Al[r][ks] = ((const bf8*)alp)[idx];
      }
    float cbl[2][4];
    #pragma unroll
    for (int r = 0; r < 2; ++r)
      #pragma unroll
      for (int j = 0; j < 4; ++j)
        cbl[r][j] = wsf[OFF_CB + b*128 + (2*w + r)*16 + lq*4 + j];

    int pbase = chunk * 512;
    for (int tile = 0; tile < 8; ++tile) {
        int tp = pbase + tile * 64;
        f4 acc[2][4];
        #pragma unroll
        for (int r = 0; r < 2; ++r)
          #pragma unroll
          for (int pt = 0; pt < 4; ++pt) acc[r][pt] = (f4){0,0,0,0};
        #pragma unroll
        for (int pt = 0; pt < 4; ++pt) {
            size_t rowoff = ((size_t)b * NN + tp + pt*16 + l15) * 128 + lq*8;
            #pragma unroll
            for (int ks = 0; ks < 4; ++ks) {
                bf8 bh = *(const bf8*)(ch + rowoff + ks*32);
                bf8 bl = *(const bf8*)(cl + rowoff + ks*32);
                #pragma unroll
                for (int r = 0; r < 2; ++r) {
                    acc[r][pt] = MFMA16(Ah[r][ks], bh, acc[r][pt]);
                    acc[r][pt] = MFMA16(Al[r][ks], bh, acc[r][pt]);
                    acc[r][pt] = MFMA16(Ah[r][ks], bl, acc[r][pt]);
                }
            }
        }
        #pragma unroll
        for (int r = 0; r < 2; ++r)
          #pragma unroll
          for (int pt = 0; pt < 4; ++pt)
            #pragma unroll
            for (int j = 0; j < 4; ++j) {
                int o = (2*w + r)*16 + lq*4 + j;
                int p = tp + pt*16 + l15;
                y[((size_t)b*128 + o)*NN + p] = acc[r][pt][j] + cbl[r][j];
            }
    }
}

// ---------------- K6 fallback (fp32 VALU), used only if workspace is small ----------------
__global__ __launch_bounds__(256) void k6_final_f32(const float* __restrict__ cond,
                                                    const float* __restrict__ wsf,
                                                    float* __restrict__ y) {
    int b = blockIdx.y;
    int tid = threadIdx.x;
    int n = blockIdx.x * 256 + tid;
    __shared__ __align__(16) float A_s[8192];
    float cnd[128];
    #pragma unroll
    for (int c = 0; c < 128; ++c) cnd[c] = cond[((size_t)b * CC + c) * NN + n];
    const float* cb = wsf + OFF_CB + b * 128;
    for (int half = 0; half < 2; ++half) {
        __syncthreads();
        {
            const float4* src = (const float4*)(wsf + OFF_AOLD + (size_t)b * 16384 + half * 8192);
            float4* dst = (float4*)A_s;
            #pragma unroll
            for (int i = 0; i < 8; ++i) dst[i * 256 + tid] = src[i * 256 + tid];
        }
        __syncthreads();
        for (int o2 = 0; o2 < 64; o2 += 2) {
            int o = half * 64 + o2;
            float acc0 = cb[o], acc1 = cb[o + 1];
            #pragma unroll
            for (int c4 = 0; c4 < 32; ++c4) {
                float4 v0 = *(const float4*)&A_s[(o2    ) * 128 + c4 * 4];
                float4 v1 = *(const float4*)&A_s[(o2 + 1) * 128 + c4 * 4];
                acc0 += v0.x*cnd[c4*4] + v0.y*cnd[c4*4+1] + v0.z*cnd[c4*4+2] + v0.w*cnd[c4*4+3];
                acc1 += v1.x*cnd[c4*4] + v1.y*cnd[c4*4+1] + v1.z*cnd[c4*4+2] + v1.w*cnd[c4*4+3];
            }
            y[((size_t)b * CC + o    ) * NN + n] = acc0;
            y[((size_t)b * CC + o + 1) * NN + n] = acc1;
        }
    }
}

extern "C" void kernel_launch(void* const* d_in, const int* in_sizes, int n_in,
                              void* d_out, int out_size, void* d_ws, size_t ws_size,
                              hipStream_t stream) {
    const float* x        = (const float*)d_in[0];
    const float* cond     = (const float*)d_in[1];
    const float* gn_scale = (const float*)d_in[2];
    const float* gn_bias  = (const float*)d_in[3];
    const float* kv_w     = (const float*)d_in[4];
    const float* kv_b     = (const float*)d_in[5];
    const float* q_w      = (const float*)d_in[6];
    const float* q_b      = (const float*)d_in[7];
    const float* out_w    = (const float*)d_in[8];
    const float* out_b    = (const float*)d_in[9];
    float* y   = (float*)d_out;
    float* wsf = (float*)d_ws;

    unsigned short* WH = (unsigned short*)(wsf + OFF_WH);
    unsigned short* AH = (unsigned short*)(wsf + OFF_AH);
    unsigned short* AL = (unsigned short*)(wsf + OFF_AL);
    float* part = wsf + OFF_PART;

    // tier2 needs xt_h+xt_l (33554432 fl) after OFF_XT
    bool big = ws_size >= (size_t)(OFF_XT + 33554432) * sizeof(float);

    unsigned short* XTH;
    unsigned short* XTL;
    if (big) {
        XTH = (unsigned short*)(wsf + OFF_XT);
        XTL = XTH + (size_t)BATCH * NN * 128;
    } else {
        XTH = (unsigned short*)y;          // consumed by k3 before k6 writes y
        XTL = XTH + (size_t)BATCH * NN * 128;
    }

    k1_gnstats<<<512, 256, 0, stream>>>(x, wsf);
    k1a_transpose<<<dim3(128, BATCH), 256, 0, stream>>>(x, XTH, XTL);
    k2_weff<<<16, 256, 0, stream>>>(kv_w, kv_b, gn_scale, gn_bias, wsf, WH);
    k3_attn<<<dim3(32, BATCH), 256, 0, stream>>>(XTH, XTL, WH, wsf, part);
    k4_reduce<<<BATCH, 256, 0, stream>>>(part, wsf, 32);
    k5_buildA<<<BATCH, 256, 0, stream>>>(out_w, q_w, q_b, out_b, wsf, AH, AL);
    if (big) {
        // reuse XT buffers for transposed cond (stream-serialized after k3)
        k1a_transpose<<<dim3(128, BATCH), 256, 0, stream>>>(cond, XTH, XTL);
        k6_mfma<<<dim3(32, BATCH), 256, 0, stream>>>(XTH, XTL, AH, AL, wsf, y);
    } else {
        k6_final_f32<<<dim3(64, BATCH), 256, 0, stream>>>(cond, wsf, y);
    }
}

// Round 3
// 272.999 us; speedup vs baseline: 4.9870x; 2.1075x over previous
//
#include <hip/hip_runtime.h>
#include <hip/hip_bf16.h>
#include <cstddef>

#define BATCH 16
#define CC 128
#define NN 16384
#define GROUPS 32
#define EPSV 1e-5f

// workspace float offsets
#define OFF_MU    0          // 512
#define OFF_RSTD  512        // 512
#define OFF_BEFF  1024       // 4096
#define OFF_CTX   5120       // 65536
#define OFF_CB    70656      // 2048
#define OFF_WH    334848     // 524288 ushorts (W_eff hi frags)
#define OFF_AH    596992     // 131072 fl (A_b hi frags)
#define OFF_AL    728064     // 131072 fl (A_b lo frags)
#define OFF_PART  859136     // 512*4224 fl
#define OFF_XT    3021824    // xt_h then xt_l (16777216 fl each)
#define PART_STRIDE 4224

typedef __attribute__((ext_vector_type(8))) short bf8;
typedef __attribute__((ext_vector_type(4))) float f4;
#define MFMA16(a,b,c) __builtin_amdgcn_mfma_f32_16x16x32_bf16(a,b,c,0,0,0)

__device__ inline unsigned short bf16_rtn(float f) {
    unsigned u = __builtin_bit_cast(unsigned, f);
    unsigned r = (u + 0x7FFFu + ((u >> 16) & 1u)) >> 16;
    return (unsigned short)r;
}
__device__ inline float bf16_f(unsigned short h) {
    unsigned u = ((unsigned)h) << 16;
    return __builtin_bit_cast(float, u);
}

// ---------------- K1: GroupNorm stats ----------------
__global__ void k1_gnstats(const float* __restrict__ x, float* __restrict__ wsf) {
    int bg = blockIdx.x;
    int tid = threadIdx.x;
    const float4* p = (const float4*)(x + (size_t)bg * 65536);
    float s = 0.f, sq = 0.f;
    #pragma unroll 4
    for (int i = 0; i < 64; ++i) {
        float4 v = p[i * 256 + tid];
        s  += v.x + v.y + v.z + v.w;
        sq += v.x*v.x + v.y*v.y + v.z*v.z + v.w*v.w;
    }
    __shared__ float rs[256], rq[256];
    rs[tid] = s; rq[tid] = sq; __syncthreads();
    for (int off = 128; off > 0; off >>= 1) {
        if (tid < off) { rs[tid] += rs[tid+off]; rq[tid] += rq[tid+off]; }
        __syncthreads();
    }
    if (tid == 0) {
        float mean = rs[0] * (1.f/65536.f);
        float var  = rq[0] * (1.f/65536.f) - mean*mean;
        wsf[OFF_MU + bg]   = mean;
        wsf[OFF_RSTD + bg] = rsqrtf(var + EPSV);
    }
}

// ---------------- K1a: transpose + bf16 hi/lo split (x only) ----------------
#define K1A_W 136
__global__ __launch_bounds__(256) void k1a_transpose(const float* __restrict__ src,
        unsigned short* __restrict__ dh, unsigned short* __restrict__ dl) {
    int b = blockIdx.y; int p0 = blockIdx.x * 128; int t = threadIdx.x;
    __shared__ unsigned short lh[128 * K1A_W], ll[128 * K1A_W];
    int p = t & 127, chalf = t >> 7;
    const float* sp = src + (size_t)b * CC * NN + p0 + p;
    #pragma unroll 8
    for (int i = 0; i < 64; ++i) {
        int c = i * 2 + chalf;
        float v = sp[(size_t)c * NN];
        unsigned short h = bf16_rtn(v);
        unsigned short l = bf16_rtn(v - bf16_f(h));
        lh[p * K1A_W + c] = h;
        ll[p * K1A_W + c] = l;
    }
    __syncthreads();
    int pr = t >> 4, c8 = (t & 15) * 8;
    #pragma unroll
    for (int j = 0; j < 8; ++j) {
        int p2 = j * 16 + pr;
        bf8 vh = *(const bf8*)&lh[p2 * K1A_W + c8];
        bf8 vl = *(const bf8*)&ll[p2 * K1A_W + c8];
        size_t off = ((size_t)b * NN + p0 + p2) * 128 + c8;
        *(bf8*)&dh[off] = vh;
        *(bf8*)&dl[off] = vl;
    }
}

// ---------------- K2: effective kv weights, bf16-hi frag-packed ----------------
__global__ void k2_weff(const float* __restrict__ kv_w, const float* __restrict__ kv_b,
                        const float* __restrict__ gn_scale, const float* __restrict__ gn_bias,
                        float* __restrict__ wsf, unsigned short* __restrict__ wh) {
    int b = blockIdx.x, o = threadIdx.x;   // 16 x 256
    const float* mu = wsf + OFF_MU + b * GROUPS;
    const float* rs = wsf + OFF_RSTD + b * GROUPS;
    float w[128]; float bacc = 0.f;
    #pragma unroll
    for (int c = 0; c < 128; ++c) {
        int g = c >> 2;
        float sc = gn_scale[c] * rs[g];
        float kw = kv_w[o * 128 + c];
        w[c] = kw * sc;
        bacc += kw * (gn_bias[c] - mu[g] * sc);
    }
    wsf[OFF_BEFF + b * 256 + o] = kv_b[o] + bacc;
    int h  = (o & 127) >> 5;
    int ct = ((o >> 4) & 1) + ((o >= 128) ? 2 : 0);
    int i  = o & 15;
    #pragma unroll
    for (int ks = 0; ks < 4; ++ks)
      #pragma unroll
      for (int eq = 0; eq < 4; ++eq) {
        bf8 pk;
        #pragma unroll
        for (int e = 0; e < 8; ++e) pk[e] = (short)bf16_rtn(w[ks*32 + eq*8 + e]);
        int lane = i + 16 * eq;
        size_t fo = ((((size_t)b * 4 + h) * 4 + ct) * 4 + ks) * 512 + (size_t)lane * 8;
        *(bf8*)&wh[fo] = pk;
      }
}

// ---------------- K3: MFMA kv-proj + streaming softmax-attention ----------------
__global__ __launch_bounds__(256, 2) void k3_attn(
    const unsigned short* __restrict__ xh, const unsigned short* __restrict__ xl,
    const unsigned short* __restrict__ wh, const float* __restrict__ wsf,
    float* __restrict__ part)
{
    int b = blockIdx.y, chunk = blockIdx.x;        // 32 chunks x 512 px
    int t = threadIdx.x, h = t >> 6, l = t & 63;
    int l15 = l & 15, lq = l >> 4;

    __shared__ unsigned short lds[4][2][32 * 64];  // [wave][ek|v][32 rows][64 px]

    bf8 W[4][4];                                    // [ct][ks], hi only
    #pragma unroll
    for (int ct = 0; ct < 4; ++ct)
      #pragma unroll
      for (int ks = 0; ks < 4; ++ks)
        W[ct][ks] = ((const bf8*)wh)[((((size_t)b*4 + h)*4 + ct)*4 + ks)*64 + l];

    float bk[4];
    #pragma unroll
    for (int ct = 0; ct < 4; ++ct) {
        int o = (ct < 2) ? (32*h + 16*ct + l15) : (128 + 32*h + 16*(ct-2) + l15);
        bk[ct] = wsf[OFF_BEFF + b * 256 + o];
    }

    bf8 ones;
    #pragma unroll
    for (int j = 0; j < 8; ++j) ones[j] = (short)0x3F80;

    f4 ctx[2][2]; f4 zac[2];
    #pragma unroll
    for (int i = 0; i < 2; ++i) {
        zac[i] = (f4){0,0,0,0};
        #pragma unroll
        for (int j = 0; j < 2; ++j) ctx[i][j] = (f4){0,0,0,0};
    }

    int pbase = chunk * 512;
    for (int tile = 0; tile < 8; ++tile) {
        int tp = pbase + tile * 64;
        f4 acc[4][4];                               // [pt][ct]
        #pragma unroll
        for (int pt = 0; pt < 4; ++pt)
          #pragma unroll
          for (int ct = 0; ct < 4; ++ct) acc[pt][ct] = (f4){0,0,0,0};

        #pragma unroll
        for (int pt = 0; pt < 4; ++pt) {
            size_t rowoff = ((size_t)b * NN + tp + pt*16 + l15) * 128 + lq * 8;
            #pragma unroll
            for (int ks = 0; ks < 4; ++ks) {
                bf8 ah = *(const bf8*)(xh + rowoff + ks*32);
                bf8 al = *(const bf8*)(xl + rowoff + ks*32);
                #pragma unroll
                for (int ct = 0; ct < 4; ++ct) {
                    acc[pt][ct] = MFMA16(ah, W[ct][ks], acc[pt][ct]);
                    acc[pt][ct] = MFMA16(al, W[ct][ks], acc[pt][ct]);
                }
            }
        }
        // bias + exp(k) -> LDS (bf16, XOR-swizzled rows)
        #pragma unroll
        for (int pt = 0; pt < 4; ++pt) {
            int p = pt * 16 + lq * 4;              // 4 consecutive px
            #pragma unroll
            for (int ct = 0; ct < 4; ++ct) {
                int row = (ct & 1) * 16 + l15;
                int sel = ct >> 1;                 // 0 = EK, 1 = V
                unsigned short pk[4];
                #pragma unroll
                for (int j = 0; j < 4; ++j) {
                    float v = acc[pt][ct][j] + bk[ct];
                    if (sel == 0) v = __expf(v);
                    pk[j] = bf16_rtn(v);
                }
                unsigned byte = ((unsigned)(row * 128 + p * 2)) ^ (((unsigned)(row & 7)) << 4);
                unsigned lo32 = (unsigned)pk[0] | ((unsigned)pk[1] << 16);
                unsigned hi32 = (unsigned)pk[2] | ((unsigned)pk[3] << 16);
                *(uint2*)((char*)&lds[h][sel][0] + byte) = make_uint2(lo32, hi32);
            }
        }
        // PV + Z (wave-local; compiler inserts lgkmcnt)
        #pragma unroll
        for (int ks2 = 0; ks2 < 2; ++ks2) {
            int p8 = ks2 * 32 + lq * 8;
            bf8 ek[2], vv[2];
            #pragma unroll
            for (int dt = 0; dt < 2; ++dt) {
                int row = dt * 16 + l15;
                unsigned byte = ((unsigned)(row * 128 + p8 * 2)) ^ (((unsigned)(row & 7)) << 4);
                ek[dt] = *(const bf8*)((char*)&lds[h][0][0] + byte);
                vv[dt] = *(const bf8*)((char*)&lds[h][1][0] + byte);
            }
            #pragma unroll
            for (int dt = 0; dt < 2; ++dt) {
                #pragma unroll
                for (int et = 0; et < 2; ++et)
                    ctx[dt][et] = MFMA16(ek[dt], vv[et], ctx[dt][et]);
                zac[dt] = MFMA16(ek[dt], ones, zac[dt]);
            }
        }
    }
    // partial write
    float* pb = part + (size_t)(b * 32 + chunk) * PART_STRIDE;
    #pragma unroll
    for (int dt = 0; dt < 2; ++dt) {
        #pragma unroll
        for (int et = 0; et < 2; ++et)
            #pragma unroll
            for (int j = 0; j < 4; ++j) {
                int d = 32*h + dt*16 + lq*4 + j;
                int e = et*16 + l15;
                pb[d * 32 + e] = ctx[dt][et][j];
            }
        if (l15 == 0)
            #pragma unroll
            for (int j = 0; j < 4; ++j)
                pb[4096 + 32*h + dt*16 + lq*4 + j] = zac[dt][j];
    }
}

// ---------------- K4: reduce partials -> context = S/Z (64 blocks) ----------------
__global__ __launch_bounds__(256) void k4_reduce(const float* __restrict__ part,
                                                 float* __restrict__ wsf, int nbpb) {
    int q = blockIdx.x, b = blockIdx.y;
    int tid = threadIdx.x;
    int hdl = tid >> 3;                 // 0..31
    int hd = q * 32 + hdl;
    int e0 = (tid & 7) * 4;
    float s[4] = {0.f, 0.f, 0.f, 0.f};
    float z = 0.f;
    for (int i = 0; i < nbpb; ++i) {
        const float* pb = part + (size_t)(b * nbpb + i) * PART_STRIDE;
        float4 v = *(const float4*)&pb[hd * 32 + e0];
        s[0] += v.x; s[1] += v.y; s[2] += v.z; s[3] += v.w;
        if ((tid & 7) == 0) z += pb[4096 + hd];
    }
    __shared__ float zs[32];
    if ((tid & 7) == 0) zs[hdl] = z;
    __syncthreads();
    float zi = 1.f / zs[hdl];
    float* cg = wsf + OFF_CTX + (size_t)b * 4096;
    #pragma unroll
    for (int j = 0; j < 4; ++j) cg[hd * 32 + e0 + j] = s[j] * zi;
}

// ---------------- K5: A_b = out_w . blockdiag(ctx^T) . q_w ; c_b ; frag-pack (128 blocks) ----------------
__global__ __launch_bounds__(256) void k5_buildA(const float* __restrict__ out_w,
                          const float* __restrict__ q_w,
                          const float* __restrict__ q_b, const float* __restrict__ out_b,
                          float* __restrict__ wsf,
                          unsigned short* __restrict__ ahp, unsigned short* __restrict__ alp) {
    int b = blockIdx.y;
    int oh = blockIdx.x * 16;           // 8 o-chunks of 16 rows
    int tid = threadIdx.x;
    __shared__ float ctx_p[128 * 33];   // pad 33: 4-way max conflict
    __shared__ float T_s[16 * 132];
    {
        const float* src = wsf + OFF_CTX + (size_t)b * 4096;
        for (int i = tid; i < 4096; i += 256)
            ctx_p[(i >> 5) * 33 + (i & 31)] = src[i];
    }
    __syncthreads();
    int ol = tid >> 4;                  // 0..15
    int o = oh + ol;
    int jb = tid & 15;                  // 0..15
    int j0 = jb * 8;
    int h = j0 >> 5;                    // constant per thread
    // phase A: T[o][j0..j0+8) = sum_e out_w[o][h*32+e] * ctx[h*32 + d][e]
    {
        float ow[32];
        #pragma unroll
        for (int e4 = 0; e4 < 8; ++e4) {
            float4 v = *(const float4*)&out_w[o * 128 + h * 32 + e4 * 4];
            ow[e4*4+0]=v.x; ow[e4*4+1]=v.y; ow[e4*4+2]=v.z; ow[e4*4+3]=v.w;
        }
        #pragma unroll
        for (int dd = 0; dd < 8; ++dd) {
            int r = h * 32 + (j0 & 31) + dd;
            const float* cp = &ctx_p[r * 33];
            float a0 = 0.f, a1 = 0.f, a2 = 0.f, a3 = 0.f;
            #pragma unroll
            for (int e = 0; e < 32; e += 4) {
                a0 += ow[e+0] * cp[e+0];
                a1 += ow[e+1] * cp[e+1];
                a2 += ow[e+2] * cp[e+2];
                a3 += ow[e+3] * cp[e+3];
            }
            T_s[ol * 132 + j0 + dd] = (a0 + a1) + (a2 + a3);
        }
    }
    __syncthreads();
    // phase B: A[o][ci0..ci0+8) = sum_j T[o][j] * q_w[j][ci]
    {
        int ci0 = jb * 8;
        float a[8];
        #pragma unroll
        for (int i = 0; i < 8; ++i) a[i] = 0.f;
        for (int j = 0; j < 128; ++j) {
            float tv = T_s[ol * 132 + j];
            float4 v0 = *(const float4*)&q_w[j * 128 + ci0];
            float4 v1 = *(const float4*)&q_w[j * 128 + ci0 + 4];
            a[0] += tv*v0.x; a[1] += tv*v0.y; a[2] += tv*v0.z; a[3] += tv*v0.w;
            a[4] += tv*v1.x; a[5] += tv*v1.y; a[6] += tv*v1.z; a[7] += tv*v1.w;
        }
        // frag-pack hi/lo
        int ks = ci0 >> 5;
        int eq = (ci0 >> 3) & 3;
        int lane = (o & 15) + 16 * eq;
        bf8 ph, pl;
        #pragma unroll
        for (int e = 0; e < 8; ++e) {
            unsigned short hh = bf16_rtn(a[e]);
            ph[e] = (short)hh;
            pl[e] = (short)bf16_rtn(a[e] - bf16_f(hh));
        }
        size_t fo = ((((size_t)b * 8 + (o >> 4)) * 4 + ks) * 64 + lane) * 8;
        *(bf8*)&ahp[fo] = ph;
        *(bf8*)&alp[fo] = pl;
        if (jb == 0) {
            float cb = 0.f;
            for (int j = 0; j < 128; ++j) cb += T_s[ol * 132 + j] * q_b[j];
            wsf[OFF_CB + b * 128 + o] = cb + out_b[o];
        }
    }
}

// ---------------- K6 (MFMA): y = A_b . cond + c_b  (reads fp32 cond directly) ----------------
__global__ __launch_bounds__(256, 2) void k6_mfma(
    const float* __restrict__ cond,
    const unsigned short* __restrict__ ahp, const unsigned short* __restrict__ alp,
    const float* __restrict__ wsf, float* __restrict__ y)
{
    int b = blockIdx.y, chunk = blockIdx.x;
    int t = threadIdx.x, w = t >> 6, l = t & 63, l15 = l & 15, lq = l >> 4;
    bf8 Ah[2][4], Al[2][4];
    #pragma unroll
    for (int r = 0; r < 2; ++r)
      #pragma unroll
      for (int ks = 0; ks < 4; ++ks) {
        size_t idx = (((size_t)b * 8 + (2*w + r)) * 4 + ks) * 64 + l;
        Ah[r][ks] = ((const bf8*)ahp)[idx];
        Al[r][ks] = ((const bf8*)alp)[idx];
      }
    float cbl[2][4];
    #pragma unroll
    for (int r = 0; r < 2; ++r)
      #pragma unroll
      for (int j = 0; j < 4; ++j)
        cbl[r][j] = wsf[OFF_CB + b*128 + (2*w + r)*16 + lq*4 + j];

    int pbase = chunk * 512;
    for (int tile = 0; tile < 8; ++tile) {
        int tp = pbase + tile * 64;
        f4 acc[2][4];
        #pragma unroll
        for (int r = 0; r < 2; ++r)
          #pragma unroll
          for (int pt = 0; pt < 4; ++pt) acc[r][pt] = (f4){0,0,0,0};
        #pragma unroll
        for (int pt = 0; pt < 4; ++pt) {
            const float* cp = cond + (size_t)b * 128 * NN + tp + pt*16 + l15;
            #pragma unroll
            for (int ks = 0; ks < 4; ++ks) {
                bf8 bh, bl;
                #pragma unroll
                for (int j = 0; j < 8; ++j) {
                    float v = cp[(size_t)(ks*32 + lq*8 + j) * NN];
                    unsigned short hh = bf16_rtn(v);
                    bh[j] = (short)hh;
                    bl[j] = (short)bf16_rtn(v - bf16_f(hh));
                }
                #pragma unroll
                for (int r = 0; r < 2; ++r) {
                    acc[r][pt] = MFMA16(Ah[r][ks], bh, acc[r][pt]);
                    acc[r][pt] = MFMA16(Al[r][ks], bh, acc[r][pt]);
                    acc[r][pt] = MFMA16(Ah[r][ks], bl, acc[r][pt]);
                }
            }
        }
        #pragma unroll
        for (int r = 0; r < 2; ++r)
          #pragma unroll
          for (int pt = 0; pt < 4; ++pt)
            #pragma unroll
            for (int j = 0; j < 4; ++j) {
                int o = (2*w + r)*16 + lq*4 + j;
                int p = tp + pt*16 + l15;
                y[((size_t)b*128 + o)*NN + p] = acc[r][pt][j] + cbl[r][j];
            }
    }
}

extern "C" void kernel_launch(void* const* d_in, const int* in_sizes, int n_in,
                              void* d_out, int out_size, void* d_ws, size_t ws_size,
                              hipStream_t stream) {
    const float* x        = (const float*)d_in[0];
    const float* cond     = (const float*)d_in[1];
    const float* gn_scale = (const float*)d_in[2];
    const float* gn_bias  = (const float*)d_in[3];
    const float* kv_w     = (const float*)d_in[4];
    const float* kv_b     = (const float*)d_in[5];
    const float* q_w      = (const float*)d_in[6];
    const float* q_b      = (const float*)d_in[7];
    const float* out_w    = (const float*)d_in[8];
    const float* out_b    = (const float*)d_in[9];
    float* y   = (float*)d_out;
    float* wsf = (float*)d_ws;

    unsigned short* WH = (unsigned short*)(wsf + OFF_WH);
    unsigned short* AH = (unsigned short*)(wsf + OFF_AH);
    unsigned short* AL = (unsigned short*)(wsf + OFF_AL);
    float* part = wsf + OFF_PART;

    bool big = ws_size >= (size_t)(OFF_XT + 33554432) * sizeof(float);

    unsigned short* XTH;
    unsigned short* XTL;
    if (big) {
        XTH = (unsigned short*)(wsf + OFF_XT);
        XTL = XTH + (size_t)BATCH * NN * 128;
    } else {
        XTH = (unsigned short*)y;          // consumed by k3 before k6 writes y
        XTL = XTH + (size_t)BATCH * NN * 128;
    }

    k1_gnstats<<<512, 256, 0, stream>>>(x, wsf);
    k1a_transpose<<<dim3(128, BATCH), 256, 0, stream>>>(x, XTH, XTL);
    k2_weff<<<16, 256, 0, stream>>>(kv_w, kv_b, gn_scale, gn_bias, wsf, WH);
    k3_attn<<<dim3(32, BATCH), 256, 0, stream>>>(XTH, XTL, WH, wsf, part);
    k4_reduce<<<dim3(4, BATCH), 256, 0, stream>>>(part, wsf, 32);
    k5_buildA<<<dim3(8, BATCH), 256, 0, stream>>>(out_w, q_w, q_b, out_b, wsf, AH, AL);
    k6_mfma<<<dim3(32, BATCH), 256, 0, stream>>>(cond, AH, AL, wsf, y);
}